// Round 15
// baseline (172.523 us; speedup 1.0000x reference)
//
#include <hip/hip_runtime.h>

#define NN 50000
#define NE 800000
#define H  64
#define NBKT 784        // buckets of 64 dst values (784*64 = 50176 >= NN)
#define BCAP 2048       // per-bucket capacity (avg ~1020, sigma ~32)
#define BIN_CHUNK 2048  // edges per k_bin binning block
#define NBIN ((NE + BIN_CHUNK - 1) / BIN_CHUNK)  // 391
#define NODE_BLKS (NN / 4)                        // 12500
#define CT4N (65 * 37)  // float4 count of c-table

typedef __attribute__((ext_vector_type(8))) short bf16x8;
typedef __attribute__((ext_vector_type(4))) float f32x4;

__device__ __forceinline__ unsigned short f2bf(float f) {
  unsigned int u = __builtin_bit_cast(unsigned int, f);
  u += 0x7FFFu + ((u >> 16) & 1u);  // RNE
  return (unsigned short)(u >> 16);
}
__device__ __forceinline__ float bf2f(unsigned short u) {
  unsigned int v = ((unsigned int)u) << 16;
  return __builtin_bit_cast(float, v);
}

// ---------- fused: node encoder (blocks 0..12499), binning (..+391), tables, w1f ----
__global__ __launch_bounds__(256) void k_bin(
    const int* __restrict__ ei, unsigned int* __restrict__ gbin,
    int* __restrict__ gcur, int* __restrict__ cnt,
    const float* __restrict__ x, const float* __restrict__ W_ne,
    const float* __restrict__ b_ne, const float* __restrict__ W_gcn,
    unsigned short* __restrict__ htb,
    const float* __restrict__ W1, const float* __restrict__ b1,
    const float* __restrict__ W_ee, const float* __restrict__ b_ee,
    float* __restrict__ thrS, float* __restrict__ cT,  // float4[65*37]
    unsigned short* __restrict__ w1f) {
  const int t = threadIdx.x;

  if (blockIdx.x < NODE_BLKS) {  // ---- node encoder + h0@W_gcn; htb UNSCALED ----
    __shared__ float sh[4][H];
    const int lane = t & 63;
    const int wv   = t >> 6;
    const int n    = blockIdx.x * 4 + wv;
    float acc = b_ne[lane];
#pragma unroll
    for (int k = 0; k < 5; ++k) acc = fmaf(x[n * 5 + k], W_ne[k * H + lane], acc);
    acc = fmaxf(acc, 0.0f);
    sh[wv][lane] = acc;
    __syncthreads();
    float hv = 0.0f;
#pragma unroll 8
    for (int k = 0; k < H; ++k) hv = fmaf(sh[wv][k], W_gcn[k * H + lane], hv);
    htb[(size_t)n * H + lane] = f2bf(hv);
    return;
  }

  if (blockIdx.x == NODE_BLKS + NBIN + 1) {  // ---- w1f fragments for uv GEMM ----
    const int ln = t & 63, q = t >> 6;
    const int l15_ = ln & 15, l4_ = ln >> 4;
#pragma unroll
    for (int f = 0; f < 4; ++f) {
      const int idx = q * 4 + f;          // 0..15
      const int g = idx >> 3;             // 0 src, 1 dst
      const int ct = (idx >> 1) & 3;      // col tile
      const int c = idx & 1;              // k chunk
#pragma unroll
      for (int j = 0; j < 8; ++j) {
        const int k = g * 64 + c * 32 + l4_ * 8 + j;
        const int hcol = ct * 16 + l15_;
        w1f[(idx * 64 + ln) * 8 + j] = f2bf(W1[k * H + hcol]);
      }
    }
    return;
  }

  if (blockIdx.x == NODE_BLKS + NBIN) {  // ---- interval tables (exact PL edge term) ----
    __shared__ float swee[64], sbee[64], sth[64];
    __shared__ int skx[64];
    if (t < 64) {
      const float w = W_ee[t], b = b_ee[t];
      swee[t] = w; sbee[t] = b;
      sth[t] = (w != 0.f) ? (-b / w) : __builtin_inff();
      skx[t] = t;
    }
    __syncthreads();
    for (int sz = 2; sz <= 64; sz <<= 1)
      for (int st = sz >> 1; st > 0; st >>= 1) {
        if (t < 64) {
          const int p = t ^ st;
          if (p > t) {
            const bool up = ((t & sz) == 0);
            const float a = sth[t], bb = sth[p];
            if (up ? (a > bb) : (a < bb)) {
              const int ka = skx[t];
              sth[t] = bb; sth[p] = a;
              skx[t] = skx[p]; skx[p] = ka;
            }
          }
        }
        __syncthreads();
      }
    if (t < 64) {
      const int h = t;
      const int l4h = h >> 4, rh = (h & 15) >> 1, sub = h & 1;
      float c1 = 0.f, c0 = b1[h];
      for (int k = 0; k < 64; ++k) {  // interval 0: ea = -inf
        const float w = swee[k], b = sbee[k];
        if (w < 0.f || (w == 0.f && b > 0.f)) {
          const float wv1 = W1[(128 + k) * H + h];
          c1 = fmaf(w, wv1, c1);
          c0 = fmaf(b, wv1, c0);
        }
      }
      {
        float* base = cT + (size_t)(0 * 37 + l4h * 9 + rh) * 4;
        base[2 * sub] = c1; base[2 * sub + 1] = c0;
      }
      for (int iv = 1; iv <= 64; ++iv) {
        const int ks = skx[iv - 1];
        const float w = swee[ks];
        const float s = (w > 0.f) ? 1.f : -1.f;
        const float wv1 = W1[(128 + ks) * H + h];
        c1 = fmaf(s * w, wv1, c1);
        c0 = fmaf(s * sbee[ks], wv1, c0);
        float* base = cT + (size_t)(iv * 37 + l4h * 9 + rh) * 4;
        base[2 * sub] = c1; base[2 * sub + 1] = c0;
      }
      thrS[h] = sth[h];
    }
    return;
  }

  // ---- binning path: blocks NODE_BLKS .. NODE_BLKS+NBIN-1 ----
  __shared__ int hist[NBKT], base[NBKT];
  for (int i = t; i < NBKT; i += 256) hist[i] = 0;
  __syncthreads();

  const int e0 = (blockIdx.x - NODE_BLKS) * BIN_CHUNK;
  int srcv[8], dstv[8], loff[8];
#pragma unroll
  for (int j = 0; j < 8; ++j) {
    const int e = e0 + j * 256 + t;
    if (e < NE) {
      srcv[j] = ei[e];
      dstv[j] = ei[NE + e];
      loff[j] = atomicAdd(&hist[dstv[j] >> 6], 1);
      atomicAdd(&cnt[dstv[j]], 1);  // global in-degree (for source-side dinv)
    } else dstv[j] = -1;
  }
  __syncthreads();
  for (int i = t; i < NBKT; i += 256) base[i] = atomicAdd(&gcur[i], hist[i]);
  __syncthreads();
#pragma unroll
  for (int j = 0; j < 8; ++j) {
    if (dstv[j] >= 0) {
      const int b = dstv[j] >> 6;
      const int pos = base[b] + loff[j];
      if (pos < BCAP)
        gbin[(size_t)b * BCAP + pos] =
            ((unsigned int)srcv[j] << 6) | (unsigned int)(dstv[j] & 63);
    }
  }
}

// ---------- fused pass2 + gather + uv: one block per 64-dst bucket ----------
__global__ __launch_bounds__(256) void k_pg(
    const unsigned int* __restrict__ gbin, const int* __restrict__ gcur,
    const int* __restrict__ cnt, const unsigned short* __restrict__ htb,
    const float* __restrict__ b_gcn, const unsigned short* __restrict__ w1f,
    unsigned short* __restrict__ u, unsigned short* __restrict__ v) {
  __shared__ int hist[64], cur[64], sc[64], sbeg[64];
  __shared__ float sdinv[64];
  __shared__ unsigned short lcsr[BCAP];     // 4KB, CSR src lists (LDS only)
  __shared__ unsigned short shg[16 * 64];   // 2KB, hg tile, XOR-swizzled rows
  const int b = blockIdx.x, t = threadIdx.x;
  const int sz = min(gcur[b], BCAP);
  if (t < 64) hist[t] = 0;
  __syncthreads();

  const unsigned int* bb = gbin + (size_t)b * BCAP;
  unsigned int ent[8];  // 8*256 = 2048 = BCAP, statically indexed
#pragma unroll
  for (int k = 0; k < 8; ++k) {
    const int i = t + k * 256;
    if (i < sz) {
      ent[k] = bb[i];
      atomicAdd(&hist[ent[k] & 63], 1);
    }
  }
  __syncthreads();

  int vinc = (t < 64) ? hist[t] : 0;
  if (t < 64) sc[t] = vinc;
  __syncthreads();
#pragma unroll
  for (int off = 1; off < 64; off <<= 1) {
    const int o = (t >= off && t < 64) ? sc[t - off] : 0;
    __syncthreads();
    if (t < 64) { vinc += o; sc[t] = vinc; }
    __syncthreads();
  }
  if (t < 64) {
    const int c = hist[t];
    const int ex = vinc - c;
    cur[t] = ex;
    sbeg[t] = ex;
    sdinv[t] = rsqrtf((float)(c + 1));
  }
  __syncthreads();

#pragma unroll
  for (int k = 0; k < 8; ++k) {
    const int i = t + k * 256;
    if (i < sz) {
      const unsigned int en = ent[k];
      const int off = atomicAdd(&cur[en & 63], 1);
      lcsr[off] = (unsigned short)(en >> 6);
    }
  }
  __syncthreads();

  // ---- gather + uv GEMM over 4 tiles of 16 nodes ----
  const int lane = t & 63, wv = t >> 6;
  const int l15 = lane & 15, l4 = lane >> 4;
  const float bg = b_gcn[lane];

  const bf16x8 bu0 = *(const bf16x8*)(w1f + ((wv * 2 + 0) * 64 + lane) * 8);
  const bf16x8 bu1 = *(const bf16x8*)(w1f + ((wv * 2 + 1) * 64 + lane) * 8);
  const bf16x8 bv0 = *(const bf16x8*)(w1f + ((8 + wv * 2 + 0) * 64 + lane) * 8);
  const bf16x8 bv1 = *(const bf16x8*)(w1f + ((8 + wv * 2 + 1) * 64 + lane) * 8);

#pragma unroll 1
  for (int tt = 0; tt < 4; ++tt) {
#pragma unroll 1
    for (int q = 0; q < 4; ++q) {
      const int nl = tt * 16 + wv * 4 + q;
      const int n = b * 64 + nl;
      float hgv = 0.f;
      if (n < NN) {
        const float dn = sdinv[nl];
        float sum = bf2f(htb[(size_t)n * H + lane]) * dn;  // self-loop
        const int beg = sbeg[nl], end = beg + hist[nl];
        int i = beg;
#pragma unroll 1
        for (; i + 4 <= end; i += 4) {
          const int s0 = lcsr[i],     s1 = lcsr[i + 1];
          const int s2 = lcsr[i + 2], s3 = lcsr[i + 3];
          const float d0 = rsqrtf((float)(cnt[s0] + 1));
          const float d1 = rsqrtf((float)(cnt[s1] + 1));
          const float d2 = rsqrtf((float)(cnt[s2] + 1));
          const float d3 = rsqrtf((float)(cnt[s3] + 1));
          const float v0 = bf2f(htb[(size_t)s0 * H + lane]);
          const float v1 = bf2f(htb[(size_t)s1 * H + lane]);
          const float v2 = bf2f(htb[(size_t)s2 * H + lane]);
          const float v3 = bf2f(htb[(size_t)s3 * H + lane]);
          sum += (v0 * d0 + v1 * d1) + (v2 * d2 + v3 * d3);
        }
#pragma unroll 1
        for (; i < end; ++i) {
          const int s = lcsr[i];
          sum = fmaf(bf2f(htb[(size_t)s * H + lane]),
                     rsqrtf((float)(cnt[s] + 1)), sum);
        }
        hgv = fmaf(dn, sum, bg);
      }
      const int rloc = nl & 15;
      shg[((rloc * 128 + lane * 2) ^ ((rloc & 7) << 4)) >> 1] = f2bf(hgv);
    }
    __syncthreads();

    const bf16x8 a0 = *(const bf16x8*)(shg + (((l15 * 128 + l4 * 16) ^ ((l15 & 7) << 4)) >> 1));
    const bf16x8 a1 = *(const bf16x8*)(shg + (((l15 * 128 + 64 + l4 * 16) ^ ((l15 & 7) << 4)) >> 1));

    f32x4 au = (f32x4)(0.f), av = (f32x4)(0.f);
    au = __builtin_amdgcn_mfma_f32_16x16x32_bf16(a0, bu0, au, 0, 0, 0);
    au = __builtin_amdgcn_mfma_f32_16x16x32_bf16(a1, bu1, au, 0, 0, 0);
    av = __builtin_amdgcn_mfma_f32_16x16x32_bf16(a0, bv0, av, 0, 0, 0);
    av = __builtin_amdgcn_mfma_f32_16x16x32_bf16(a1, bv1, av, 0, 0, 0);

#pragma unroll
    for (int r = 0; r < 4; ++r) {  // D: row = l4*4+r (node), col = l15
      const int nw = b * 64 + tt * 16 + l4 * 4 + r;
      if (nw < NN) {
        const size_t idx = (size_t)nw * H + wv * 16 + l15;
        u[idx] = f2bf(au[r]);
        v[idx] = f2bf(av[r]);
      }
    }
    __syncthreads();  // shg reused next tile
  }
}

// ---------- edge kernel helpers ----------
__device__ __forceinline__ int find_iv(const float* __restrict__ sThr, float ea) {
  int iv = 0;
#pragma unroll
  for (int st = 64; st >= 1; st >>= 1) {
    const int nc = iv + st;
    if (nc <= 64 && sThr[nc - 1] <= ea) iv = nc;
  }
  return iv;
}

__device__ __forceinline__ void edge_compute(
    float ea, uint4 U0, uint4 U1, uint4 V0, uint4 V1,
    const float* __restrict__ sThr, const float4* __restrict__ sCT4,
    const float* __restrict__ w2v, int l4, int lane, float b2v,
    float* __restrict__ out, int obase) {
  const int iv = find_iv(sThr, ea);
  const float4* cp = sCT4 + iv * 37 + l4 * 9;  // bank-spread layout
  const unsigned int ud[8] = {U0.x, U0.y, U0.z, U0.w, U1.x, U1.y, U1.z, U1.w};
  const unsigned int vd[8] = {V0.x, V0.y, V0.z, V0.w, V1.x, V1.y, V1.z, V1.w};
  float p = 0.f;
#pragma unroll
  for (int r = 0; r < 8; ++r) {
    const float4 cc = cp[r];  // (c1,c0) for h = l4*16 + 2r, 2r+1
    const float ulo = __builtin_bit_cast(float, ud[r] << 16);
    const float uhi = __builtin_bit_cast(float, ud[r] & 0xFFFF0000u);
    const float vlo = __builtin_bit_cast(float, vd[r] << 16);
    const float vhi = __builtin_bit_cast(float, vd[r] & 0xFFFF0000u);
    const float z0 = ulo + vlo + fmaf(ea, cc.x, cc.y);
    const float z1 = uhi + vhi + fmaf(ea, cc.z, cc.w);
    p = fmaf(fmaxf(z0, 0.f), w2v[2 * r], p);
    p = fmaf(fmaxf(z1, 0.f), w2v[2 * r + 1], p);
  }
  p += __shfl_xor(p, 16);
  p += __shfl_xor(p, 32);
  if (lane < 16) out[obase + lane] = p + b2v;
}

// ---------- edge kernel: 512 threads (8 waves), LDS sCT4, 2-deep pipeline ----------
#define ET 5  // block covers 8*5*16 = 640 edges; grid = 1250
__global__ __launch_bounds__(512) void k_edge(
    const int* __restrict__ ei, const float* __restrict__ eattr,
    const unsigned short* __restrict__ u, const unsigned short* __restrict__ v,
    const float* __restrict__ thrS, const float* __restrict__ cT,
    const float* __restrict__ W2, const float* __restrict__ b2,
    float* __restrict__ out) {
  __shared__ float sThr[64];
  __shared__ float4 sCT4[CT4N];  // 38,480 B

  const int t = threadIdx.x;
  if (t < 64) sThr[t] = thrS[t];
  {
    const float4* g = (const float4*)cT;
    for (int i = t; i < CT4N; i += 512) sCT4[i] = g[i];
  }
  __syncthreads();

  const int lane = t & 63;
  const int wv   = t >> 6;  // 0..7
  const int l15  = lane & 15, l4 = lane >> 4;
  const float b2v = b2[0];

  float w2v[16];
#pragma unroll
  for (int j = 0; j < 16; ++j) w2v[j] = W2[l4 * 16 + j];

  const int tile0 = (blockIdx.x * 8 + wv) * ET;
  int srcA[ET], dstA[ET];
  float eaA[ET];
#pragma unroll
  for (int tt = 0; tt < ET; ++tt) {
    srcA[tt] = ei[(tile0 + tt) * 16 + l15];
    dstA[tt] = ei[NE + (tile0 + tt) * 16 + l15];
    eaA[tt]  = eattr[(tile0 + tt) * 16 + l15];
  }

  uint4 Au0, Au1, Av0, Av1, Bu0, Bu1, Bv0, Bv1;

#define LOADUV(U0, U1, V0, V1, tt) {                               \
    const unsigned short* up = u + (size_t)srcA[tt] * H + l4 * 16; \
    const unsigned short* vp = v + (size_t)dstA[tt] * H + l4 * 16; \
    U0 = *(const uint4*)(up); U1 = *(const uint4*)(up + 8);        \
    V0 = *(const uint4*)(vp); V1 = *(const uint4*)(vp + 8); }

  LOADUV(Au0, Au1, Av0, Av1, 0);
  LOADUV(Bu0, Bu1, Bv0, Bv1, 1);
  edge_compute(eaA[0], Au0, Au1, Av0, Av1, sThr, sCT4, w2v, l4, lane, b2v, out, (tile0 + 0) * 16);
  LOADUV(Au0, Au1, Av0, Av1, 2);
  edge_compute(eaA[1], Bu0, Bu1, Bv0, Bv1, sThr, sCT4, w2v, l4, lane, b2v, out, (tile0 + 1) * 16);
  LOADUV(Bu0, Bu1, Bv0, Bv1, 3);
  edge_compute(eaA[2], Au0, Au1, Av0, Av1, sThr, sCT4, w2v, l4, lane, b2v, out, (tile0 + 2) * 16);
  LOADUV(Au0, Au1, Av0, Av1, 4);
  edge_compute(eaA[3], Bu0, Bu1, Bv0, Bv1, sThr, sCT4, w2v, l4, lane, b2v, out, (tile0 + 3) * 16);
  edge_compute(eaA[4], Au0, Au1, Av0, Av1, sThr, sCT4, w2v, l4, lane, b2v, out, (tile0 + 4) * 16);
#undef LOADUV
}

extern "C" void kernel_launch(void* const* d_in, const int* in_sizes, int n_in,
                              void* d_out, int out_size, void* d_ws, size_t ws_size,
                              hipStream_t stream) {
  const float* x     = (const float*)d_in[0];
  const int*   ei    = (const int*)d_in[1];
  const float* eattr = (const float*)d_in[2];
  const float* W_ne  = (const float*)d_in[3];
  const float* b_ne  = (const float*)d_in[4];
  const float* W_ee  = (const float*)d_in[5];
  const float* b_ee  = (const float*)d_in[6];
  const float* W_gcn = (const float*)d_in[7];
  const float* b_gcn = (const float*)d_in[8];
  const float* W1    = (const float*)d_in[9];
  const float* b1    = (const float*)d_in[10];
  const float* W2    = (const float*)d_in[11];
  const float* b2    = (const float*)d_in[12];
  float* out = (float*)d_out;

  char* ws = (char*)d_ws;
  unsigned short* htb = (unsigned short*)(ws + 0);         // 6.4MB (UNSCALED ht)
  unsigned short* uT  = (unsigned short*)(ws + 6400000);   // 6.4MB
  unsigned int*   gbin = (unsigned int*)(ws + 12800000);   // 784*2048*4 = 6,422,528
  unsigned short* vT  = (unsigned short*)(ws + 12800000);  // overlays gbin (block-local)
  int*   cnt     = (int*)(ws + 19222528);                  // 200,000
  int*   gcur    = (int*)(ws + 19422528);                  // 3,136
  float* thrS    = (float*)(ws + 19425664);                // 256
  float* cT      = (float*)(ws + 19425920);                // float4[65*37] = 38,480
  unsigned short* w1f = (unsigned short*)(ws + 19464400);  // 16,384

  hipMemsetAsync(cnt, 0, 200000 + 3136, stream);  // cnt + gcur (adjacent)
  k_bin<<<NODE_BLKS + NBIN + 2, 256, 0, stream>>>(
      ei, gbin, gcur, cnt, x, W_ne, b_ne, W_gcn, htb,
      W1, b1, W_ee, b_ee, thrS, cT, w1f);
  k_pg<<<NBKT, 256, 0, stream>>>(gbin, gcur, cnt, htb, b_gcn, w1f, uT, vT);
  k_edge<<<NE / (8 * ET * 16), 512, 0, stream>>>(ei, eattr, uT, vT, thrS, cT, W2, b2, out);
}

// Round 16
// 165.629 us; speedup vs baseline: 1.0416x; 1.0416x over previous
//
#include <hip/hip_runtime.h>

#define NN 50000
#define NE 800000
#define H  64
#define NBKT 784        // buckets of 64 dst values (784*64 = 50176 >= NN)
#define BCAP 2048       // per-bucket capacity (avg ~1020, sigma ~32)
#define BIN_CHUNK 2048  // edges per k_bin binning block
#define NBIN ((NE + BIN_CHUNK - 1) / BIN_CHUNK)  // 391
#define NODE_BLKS (NN / 4)                        // 12500
#define CT4N (65 * 37)  // float4 count of c-table

typedef __attribute__((ext_vector_type(8))) short bf16x8;
typedef __attribute__((ext_vector_type(4))) float f32x4;

__device__ __forceinline__ unsigned short f2bf(float f) {
  unsigned int u = __builtin_bit_cast(unsigned int, f);
  u += 0x7FFFu + ((u >> 16) & 1u);  // RNE
  return (unsigned short)(u >> 16);
}
__device__ __forceinline__ float bf2f(unsigned short u) {
  unsigned int v = ((unsigned int)u) << 16;
  return __builtin_bit_cast(float, v);
}

// ---------- fused: tables (blk 0), w1f (blk 1), binning (2..392), node enc (rest) ----
__global__ __launch_bounds__(256) void k_bin(
    const int* __restrict__ ei, unsigned int* __restrict__ gbin,
    int* __restrict__ gcur, int* __restrict__ cnt,
    const float* __restrict__ x, const float* __restrict__ W_ne,
    const float* __restrict__ b_ne, const float* __restrict__ W_gcn,
    unsigned short* __restrict__ htb,
    const float* __restrict__ W1, const float* __restrict__ b1,
    const float* __restrict__ W_ee, const float* __restrict__ b_ee,
    float* __restrict__ thrS, float* __restrict__ cT,  // float4[65*37]
    unsigned short* __restrict__ w1f) {
  const int t = threadIdx.x;

  if (blockIdx.x == 0) {  // ---- interval tables; W1 tail staged in LDS ----
    __shared__ float sW1[64][65];  // rows 128..191 of W1, [k][h], padded
    __shared__ float swee[64], sbee[64], sth[64];
    __shared__ int skx[64];
    for (int i = t; i < 64 * 64; i += 256) {
      const int k = i >> 6, h = i & 63;
      sW1[k][h] = W1[(128 + k) * H + h];
    }
    if (t < 64) {
      const float w = W_ee[t], b = b_ee[t];
      swee[t] = w; sbee[t] = b;
      sth[t] = (w != 0.f) ? (-b / w) : __builtin_inff();
      skx[t] = t;
    }
    __syncthreads();
    for (int sz = 2; sz <= 64; sz <<= 1)
      for (int st = sz >> 1; st > 0; st >>= 1) {
        if (t < 64) {
          const int p = t ^ st;
          if (p > t) {
            const bool up = ((t & sz) == 0);
            const float a = sth[t], bb = sth[p];
            if (up ? (a > bb) : (a < bb)) {
              const int ka = skx[t];
              sth[t] = bb; sth[p] = a;
              skx[t] = skx[p]; skx[p] = ka;
            }
          }
        }
        __syncthreads();
      }
    if (t < 64) {
      const int h = t;
      const int l4h = h >> 4, rh = (h & 15) >> 1, sub = h & 1;
      float c1 = 0.f, c0 = b1[h];
      for (int k = 0; k < 64; ++k) {  // interval 0: ea = -inf
        const float w = swee[k], b = sbee[k];
        if (w < 0.f || (w == 0.f && b > 0.f)) {
          const float wv1 = sW1[k][h];
          c1 = fmaf(w, wv1, c1);
          c0 = fmaf(b, wv1, c0);
        }
      }
      {
        float* base = cT + (size_t)(0 * 37 + l4h * 9 + rh) * 4;
        base[2 * sub] = c1; base[2 * sub + 1] = c0;
      }
      for (int iv = 1; iv <= 64; ++iv) {
        const int ks = skx[iv - 1];
        const float w = swee[ks];
        const float s = (w > 0.f) ? 1.f : -1.f;
        const float wv1 = sW1[ks][h];
        c1 = fmaf(s * w, wv1, c1);
        c0 = fmaf(s * sbee[ks], wv1, c0);
        float* base = cT + (size_t)(iv * 37 + l4h * 9 + rh) * 4;
        base[2 * sub] = c1; base[2 * sub + 1] = c0;
      }
      thrS[h] = sth[h];
    }
    return;
  }

  if (blockIdx.x == 1) {  // ---- w1f fragments for uv GEMM ----
    const int ln = t & 63, q = t >> 6;
    const int l15_ = ln & 15, l4_ = ln >> 4;
#pragma unroll
    for (int f = 0; f < 4; ++f) {
      const int idx = q * 4 + f;          // 0..15
      const int g = idx >> 3;             // 0 src, 1 dst
      const int ct = (idx >> 1) & 3;      // col tile
      const int c = idx & 1;              // k chunk
#pragma unroll
      for (int j = 0; j < 8; ++j) {
        const int k = g * 64 + c * 32 + l4_ * 8 + j;
        const int hcol = ct * 16 + l15_;
        w1f[(idx * 64 + ln) * 8 + j] = f2bf(W1[k * H + hcol]);
      }
    }
    return;
  }

  if (blockIdx.x < 2 + NBIN) {  // ---- binning path ----
    __shared__ int hist[NBKT], base[NBKT];
    for (int i = t; i < NBKT; i += 256) hist[i] = 0;
    __syncthreads();

    const int e0 = (blockIdx.x - 2) * BIN_CHUNK;
    int srcv[8], dstv[8], loff[8];
#pragma unroll
    for (int j = 0; j < 8; ++j) {
      const int e = e0 + j * 256 + t;
      if (e < NE) {
        srcv[j] = ei[e];
        dstv[j] = ei[NE + e];
        loff[j] = atomicAdd(&hist[dstv[j] >> 6], 1);
        atomicAdd(&cnt[dstv[j]], 1);  // global in-degree (for source-side dinv)
      } else dstv[j] = -1;
    }
    __syncthreads();
    for (int i = t; i < NBKT; i += 256) base[i] = atomicAdd(&gcur[i], hist[i]);
    __syncthreads();
#pragma unroll
    for (int j = 0; j < 8; ++j) {
      if (dstv[j] >= 0) {
        const int b = dstv[j] >> 6;
        const int pos = base[b] + loff[j];
        if (pos < BCAP)
          gbin[(size_t)b * BCAP + pos] =
              ((unsigned int)srcv[j] << 6) | (unsigned int)(dstv[j] & 63);
      }
    }
    return;
  }

  // ---- node encoder + h0@W_gcn; htb UNSCALED ----
  {
    __shared__ float sh[4][H];
    const int lane = t & 63;
    const int wv   = t >> 6;
    const int n    = (blockIdx.x - 2 - NBIN) * 4 + wv;
    float acc = b_ne[lane];
#pragma unroll
    for (int k = 0; k < 5; ++k) acc = fmaf(x[n * 5 + k], W_ne[k * H + lane], acc);
    acc = fmaxf(acc, 0.0f);
    sh[wv][lane] = acc;
    __syncthreads();
    float hv = 0.0f;
#pragma unroll 8
    for (int k = 0; k < H; ++k) hv = fmaf(sh[wv][k], W_gcn[k * H + lane], hv);
    htb[(size_t)n * H + lane] = f2bf(hv);
  }
}

// ---------- fused pass2 + gather + uv: one block per 64-dst bucket ----------
__global__ __launch_bounds__(256) void k_pg(
    const unsigned int* __restrict__ gbin, const int* __restrict__ gcur,
    const int* __restrict__ cnt, const unsigned short* __restrict__ htb,
    const float* __restrict__ b_gcn, const unsigned short* __restrict__ w1f,
    unsigned short* __restrict__ u, unsigned short* __restrict__ v) {
  __shared__ int hist[64], cur[64], sc[64], sbeg[64];
  __shared__ float sdinv[64];
  __shared__ unsigned short lcsr[BCAP];     // 4KB, CSR src lists (LDS only)
  __shared__ unsigned short shg[16 * 64];   // 2KB, hg tile, XOR-swizzled rows
  const int b = blockIdx.x, t = threadIdx.x;
  const int sz = min(gcur[b], BCAP);
  if (t < 64) hist[t] = 0;
  __syncthreads();

  const unsigned int* bb = gbin + (size_t)b * BCAP;
  unsigned int ent[8];  // 8*256 = 2048 = BCAP, statically indexed
#pragma unroll
  for (int k = 0; k < 8; ++k) {
    const int i = t + k * 256;
    if (i < sz) {
      ent[k] = bb[i];
      atomicAdd(&hist[ent[k] & 63], 1);
    }
  }
  __syncthreads();

  int vinc = (t < 64) ? hist[t] : 0;
  if (t < 64) sc[t] = vinc;
  __syncthreads();
#pragma unroll
  for (int off = 1; off < 64; off <<= 1) {
    const int o = (t >= off && t < 64) ? sc[t - off] : 0;
    __syncthreads();
    if (t < 64) { vinc += o; sc[t] = vinc; }
    __syncthreads();
  }
  if (t < 64) {
    const int c = hist[t];
    const int ex = vinc - c;
    cur[t] = ex;
    sbeg[t] = ex;
    sdinv[t] = rsqrtf((float)(c + 1));
  }
  __syncthreads();

#pragma unroll
  for (int k = 0; k < 8; ++k) {
    const int i = t + k * 256;
    if (i < sz) {
      const unsigned int en = ent[k];
      const int off = atomicAdd(&cur[en & 63], 1);
      lcsr[off] = (unsigned short)(en >> 6);
    }
  }
  __syncthreads();

  // ---- gather + uv GEMM over 4 tiles of 16 nodes ----
  const int lane = t & 63, wv = t >> 6;
  const int l15 = lane & 15, l4 = lane >> 4;
  const float bg = b_gcn[lane];

  const bf16x8 bu0 = *(const bf16x8*)(w1f + ((wv * 2 + 0) * 64 + lane) * 8);
  const bf16x8 bu1 = *(const bf16x8*)(w1f + ((wv * 2 + 1) * 64 + lane) * 8);
  const bf16x8 bv0 = *(const bf16x8*)(w1f + ((8 + wv * 2 + 0) * 64 + lane) * 8);
  const bf16x8 bv1 = *(const bf16x8*)(w1f + ((8 + wv * 2 + 1) * 64 + lane) * 8);

#pragma unroll 1
  for (int tt = 0; tt < 4; ++tt) {
#pragma unroll 1
    for (int q = 0; q < 4; ++q) {
      const int nl = tt * 16 + wv * 4 + q;
      const int n = b * 64 + nl;
      float hgv = 0.f;
      if (n < NN) {
        const float dn = sdinv[nl];
        float sum = bf2f(htb[(size_t)n * H + lane]) * dn;  // self-loop
        const int beg = sbeg[nl], end = beg + hist[nl];
        int i = beg;
#pragma unroll 1
        for (; i + 4 <= end; i += 4) {
          const int s0 = lcsr[i],     s1 = lcsr[i + 1];
          const int s2 = lcsr[i + 2], s3 = lcsr[i + 3];
          const float d0 = rsqrtf((float)(cnt[s0] + 1));
          const float d1 = rsqrtf((float)(cnt[s1] + 1));
          const float d2 = rsqrtf((float)(cnt[s2] + 1));
          const float d3 = rsqrtf((float)(cnt[s3] + 1));
          const float v0 = bf2f(htb[(size_t)s0 * H + lane]);
          const float v1 = bf2f(htb[(size_t)s1 * H + lane]);
          const float v2 = bf2f(htb[(size_t)s2 * H + lane]);
          const float v3 = bf2f(htb[(size_t)s3 * H + lane]);
          sum += (v0 * d0 + v1 * d1) + (v2 * d2 + v3 * d3);
        }
#pragma unroll 1
        for (; i < end; ++i) {
          const int s = lcsr[i];
          sum = fmaf(bf2f(htb[(size_t)s * H + lane]),
                     rsqrtf((float)(cnt[s] + 1)), sum);
        }
        hgv = fmaf(dn, sum, bg);
      }
      const int rloc = nl & 15;
      shg[((rloc * 128 + lane * 2) ^ ((rloc & 7) << 4)) >> 1] = f2bf(hgv);
    }
    __syncthreads();

    const bf16x8 a0 = *(const bf16x8*)(shg + (((l15 * 128 + l4 * 16) ^ ((l15 & 7) << 4)) >> 1));
    const bf16x8 a1 = *(const bf16x8*)(shg + (((l15 * 128 + 64 + l4 * 16) ^ ((l15 & 7) << 4)) >> 1));

    f32x4 au = (f32x4)(0.f), av = (f32x4)(0.f);
    au = __builtin_amdgcn_mfma_f32_16x16x32_bf16(a0, bu0, au, 0, 0, 0);
    au = __builtin_amdgcn_mfma_f32_16x16x32_bf16(a1, bu1, au, 0, 0, 0);
    av = __builtin_amdgcn_mfma_f32_16x16x32_bf16(a0, bv0, av, 0, 0, 0);
    av = __builtin_amdgcn_mfma_f32_16x16x32_bf16(a1, bv1, av, 0, 0, 0);

#pragma unroll
    for (int r = 0; r < 4; ++r) {  // D: row = l4*4+r (node), col = l15
      const int nw = b * 64 + tt * 16 + l4 * 4 + r;
      if (nw < NN) {
        const size_t idx = (size_t)nw * H + wv * 16 + l15;
        u[idx] = f2bf(au[r]);
        v[idx] = f2bf(av[r]);
      }
    }
    __syncthreads();  // shg reused next tile
  }
}

// ---------- edge kernel helpers ----------
__device__ __forceinline__ int find_iv(const float* __restrict__ sThr, float ea) {
  int iv = 0;
#pragma unroll
  for (int st = 64; st >= 1; st >>= 1) {
    const int nc = iv + st;
    if (nc <= 64 && sThr[nc - 1] <= ea) iv = nc;
  }
  return iv;
}

__device__ __forceinline__ void edge_compute(
    float ea, uint4 U0, uint4 U1, uint4 V0, uint4 V1,
    const float* __restrict__ sThr, const float4* __restrict__ sCT4,
    const float* __restrict__ w2v, int l4, int lane, float b2v,
    float* __restrict__ out, int obase) {
  const int iv = find_iv(sThr, ea);
  const float4* cp = sCT4 + iv * 37 + l4 * 9;  // bank-spread layout
  const unsigned int ud[8] = {U0.x, U0.y, U0.z, U0.w, U1.x, U1.y, U1.z, U1.w};
  const unsigned int vd[8] = {V0.x, V0.y, V0.z, V0.w, V1.x, V1.y, V1.z, V1.w};
  float p = 0.f;
#pragma unroll
  for (int r = 0; r < 8; ++r) {
    const float4 cc = cp[r];  // (c1,c0) for h = l4*16 + 2r, 2r+1
    const float ulo = __builtin_bit_cast(float, ud[r] << 16);
    const float uhi = __builtin_bit_cast(float, ud[r] & 0xFFFF0000u);
    const float vlo = __builtin_bit_cast(float, vd[r] << 16);
    const float vhi = __builtin_bit_cast(float, vd[r] & 0xFFFF0000u);
    const float z0 = ulo + vlo + fmaf(ea, cc.x, cc.y);
    const float z1 = uhi + vhi + fmaf(ea, cc.z, cc.w);
    p = fmaf(fmaxf(z0, 0.f), w2v[2 * r], p);
    p = fmaf(fmaxf(z1, 0.f), w2v[2 * r + 1], p);
  }
  p += __shfl_xor(p, 16);
  p += __shfl_xor(p, 32);
  if (lane < 16) out[obase + lane] = p + b2v;
}

// ---------- edge kernel: 512 threads (8 waves), LDS sCT4, 2-deep pipeline ----------
#define ET 5  // block covers 8*5*16 = 640 edges; grid = 1250
__global__ __launch_bounds__(512) void k_edge(
    const int* __restrict__ ei, const float* __restrict__ eattr,
    const unsigned short* __restrict__ u, const unsigned short* __restrict__ v,
    const float* __restrict__ thrS, const float* __restrict__ cT,
    const float* __restrict__ W2, const float* __restrict__ b2,
    float* __restrict__ out) {
  __shared__ float sThr[64];
  __shared__ float4 sCT4[CT4N];  // 38,480 B

  const int t = threadIdx.x;
  if (t < 64) sThr[t] = thrS[t];
  {
    const float4* g = (const float4*)cT;
    for (int i = t; i < CT4N; i += 512) sCT4[i] = g[i];
  }
  __syncthreads();

  const int lane = t & 63;
  const int wv   = t >> 6;  // 0..7
  const int l15  = lane & 15, l4 = lane >> 4;
  const float b2v = b2[0];

  float w2v[16];
#pragma unroll
  for (int j = 0; j < 16; ++j) w2v[j] = W2[l4 * 16 + j];

  const int tile0 = (blockIdx.x * 8 + wv) * ET;
  int srcA[ET], dstA[ET];
  float eaA[ET];
#pragma unroll
  for (int tt = 0; tt < ET; ++tt) {
    srcA[tt] = ei[(tile0 + tt) * 16 + l15];
    dstA[tt] = ei[NE + (tile0 + tt) * 16 + l15];
    eaA[tt]  = eattr[(tile0 + tt) * 16 + l15];
  }

  uint4 Au0, Au1, Av0, Av1, Bu0, Bu1, Bv0, Bv1;

#define LOADUV(U0, U1, V0, V1, tt) {                               \
    const unsigned short* up = u + (size_t)srcA[tt] * H + l4 * 16; \
    const unsigned short* vp = v + (size_t)dstA[tt] * H + l4 * 16; \
    U0 = *(const uint4*)(up); U1 = *(const uint4*)(up + 8);        \
    V0 = *(const uint4*)(vp); V1 = *(const uint4*)(vp + 8); }

  LOADUV(Au0, Au1, Av0, Av1, 0);
  LOADUV(Bu0, Bu1, Bv0, Bv1, 1);
  edge_compute(eaA[0], Au0, Au1, Av0, Av1, sThr, sCT4, w2v, l4, lane, b2v, out, (tile0 + 0) * 16);
  LOADUV(Au0, Au1, Av0, Av1, 2);
  edge_compute(eaA[1], Bu0, Bu1, Bv0, Bv1, sThr, sCT4, w2v, l4, lane, b2v, out, (tile0 + 1) * 16);
  LOADUV(Bu0, Bu1, Bv0, Bv1, 3);
  edge_compute(eaA[2], Au0, Au1, Av0, Av1, sThr, sCT4, w2v, l4, lane, b2v, out, (tile0 + 2) * 16);
  LOADUV(Au0, Au1, Av0, Av1, 4);
  edge_compute(eaA[3], Bu0, Bu1, Bv0, Bv1, sThr, sCT4, w2v, l4, lane, b2v, out, (tile0 + 3) * 16);
  edge_compute(eaA[4], Au0, Au1, Av0, Av1, sThr, sCT4, w2v, l4, lane, b2v, out, (tile0 + 4) * 16);
#undef LOADUV
}

extern "C" void kernel_launch(void* const* d_in, const int* in_sizes, int n_in,
                              void* d_out, int out_size, void* d_ws, size_t ws_size,
                              hipStream_t stream) {
  const float* x     = (const float*)d_in[0];
  const int*   ei    = (const int*)d_in[1];
  const float* eattr = (const float*)d_in[2];
  const float* W_ne  = (const float*)d_in[3];
  const float* b_ne  = (const float*)d_in[4];
  const float* W_ee  = (const float*)d_in[5];
  const float* b_ee  = (const float*)d_in[6];
  const float* W_gcn = (const float*)d_in[7];
  const float* b_gcn = (const float*)d_in[8];
  const float* W1    = (const float*)d_in[9];
  const float* b1    = (const float*)d_in[10];
  const float* W2    = (const float*)d_in[11];
  const float* b2    = (const float*)d_in[12];
  float* out = (float*)d_out;

  char* ws = (char*)d_ws;
  unsigned short* htb = (unsigned short*)(ws + 0);         // 6.4MB (UNSCALED ht)
  unsigned short* uT  = (unsigned short*)(ws + 6400000);   // 6.4MB
  unsigned int*   gbin = (unsigned int*)(ws + 12800000);   // 784*2048*4 = 6,422,528
  unsigned short* vT  = (unsigned short*)(ws + 12800000);  // overlays gbin (block-local)
  int*   cnt     = (int*)(ws + 19222528);                  // 200,000
  int*   gcur    = (int*)(ws + 19422528);                  // 3,136
  float* thrS    = (float*)(ws + 19425664);                // 256
  float* cT      = (float*)(ws + 19425920);                // float4[65*37] = 38,480
  unsigned short* w1f = (unsigned short*)(ws + 19464400);  // 16,384

  hipMemsetAsync(cnt, 0, 200000 + 3136, stream);  // cnt + gcur (adjacent)
  k_bin<<<NODE_BLKS + NBIN + 2, 256, 0, stream>>>(
      ei, gbin, gcur, cnt, x, W_ne, b_ne, W_gcn, htb,
      W1, b1, W_ee, b_ee, thrS, cT, w1f);
  k_pg<<<NBKT, 256, 0, stream>>>(gbin, gcur, cnt, htb, b_gcn, w1f, uT, vT);
  k_edge<<<NE / (8 * ET * 16), 512, 0, stream>>>(ei, eattr, uT, vT, thrS, cT, W2, b2, out);
}

// Round 17
// 143.118 us; speedup vs baseline: 1.2055x; 1.1573x over previous
//
#include <hip/hip_runtime.h>

#define NN 50000
#define NE 800000
#define H  64
#define NBKT 196        // buckets of 256 dst values (196*256 = 50176 >= NN)
#define BCAP 8192       // per-bucket capacity (avg ~4082)
#define BIN_CHUNK 2048  // edges per k_bin block
#define NBIN ((NE + BIN_CHUNK - 1) / BIN_CHUNK)  // 391
#define CT4N (65 * 37)  // float4 count of c-table
#define ET 5            // tiles per wave per chunk
#define ECHUNK 2        // chunks per k_edge block; grid = 625

typedef __attribute__((ext_vector_type(8))) short bf16x8;
typedef __attribute__((ext_vector_type(4))) float f32x4;

__device__ __forceinline__ unsigned short f2bf(float f) {
  unsigned int u = __builtin_bit_cast(unsigned int, f);
  u += 0x7FFFu + ((u >> 16) & 1u);  // RNE
  return (unsigned short)(u >> 16);
}
__device__ __forceinline__ float bf2f(unsigned short u) {
  unsigned int v = ((unsigned int)u) << 16;
  return __builtin_bit_cast(float, v);
}

// ---------- pass 1 + prep: bin edges (blocks 0..390); tables (391); w1f (392) ----------
__global__ __launch_bounds__(256) void k_bin(
    const int* __restrict__ ei, unsigned int* __restrict__ gbin,
    int* __restrict__ gcur,
    const float* __restrict__ W1, const float* __restrict__ b1,
    const float* __restrict__ W_ee, const float* __restrict__ b_ee,
    float* __restrict__ thrS, float* __restrict__ cT,  // float4[65*37] layout
    unsigned short* __restrict__ w1f) {
  const int t = threadIdx.x;

  if (blockIdx.x == NBIN + 1) {  // W1 src/dst blocks -> 16 B-fragments for uv GEMM
    const int ln = t & 63, q = t >> 6;
    const int l15_ = ln & 15, l4_ = ln >> 4;
#pragma unroll
    for (int f = 0; f < 4; ++f) {
      const int idx = q * 4 + f;          // 0..15
      const int g = idx >> 3;             // 0 src, 1 dst
      const int ct = (idx >> 1) & 3;      // col tile
      const int c = idx & 1;              // k chunk
#pragma unroll
      for (int j = 0; j < 8; ++j) {
        const int k = g * 64 + c * 32 + l4_ * 8 + j;
        const int hcol = ct * 16 + l15_;
        w1f[(idx * 64 + ln) * 8 + j] = f2bf(W1[k * H + hcol]);
      }
    }
    return;
  }

  if (blockIdx.x == NBIN) {  // interval tables; W1 tail staged in LDS
    __shared__ float sW1[64][65];  // rows 128..191 of W1, [k][h], padded
    __shared__ float swee[64], sbee[64], sth[64];
    __shared__ int skx[64];
    for (int i = t; i < 64 * 64; i += 256) {
      const int k = i >> 6, h = i & 63;
      sW1[k][h] = W1[(128 + k) * H + h];
    }
    if (t < 64) {
      const float w = W_ee[t], b = b_ee[t];
      swee[t] = w; sbee[t] = b;
      sth[t] = (w != 0.f) ? (-b / w) : __builtin_inff();
      skx[t] = t;
    }
    __syncthreads();
    for (int sz = 2; sz <= 64; sz <<= 1)
      for (int st = sz >> 1; st > 0; st >>= 1) {
        if (t < 64) {
          const int p = t ^ st;
          if (p > t) {
            const bool up = ((t & sz) == 0);
            const float a = sth[t], bb = sth[p];
            if (up ? (a > bb) : (a < bb)) {
              const int ka = skx[t];
              sth[t] = bb; sth[p] = a;
              skx[t] = skx[p]; skx[p] = ka;
            }
          }
        }
        __syncthreads();
      }
    if (t < 64) {
      const int h = t;
      const int l4h = h >> 4, rh = (h & 15) >> 1, sub = h & 1;
      float c1 = 0.f, c0 = b1[h];
      for (int k = 0; k < 64; ++k) {  // interval 0: ea = -inf
        const float w = swee[k], b = sbee[k];
        if (w < 0.f || (w == 0.f && b > 0.f)) {
          const float wv1 = sW1[k][h];
          c1 = fmaf(w, wv1, c1);
          c0 = fmaf(b, wv1, c0);
        }
      }
      {
        float* base = cT + (size_t)(0 * 37 + l4h * 9 + rh) * 4;
        base[2 * sub] = c1; base[2 * sub + 1] = c0;
      }
      for (int iv = 1; iv <= 64; ++iv) {
        const int ks = skx[iv - 1];
        const float w = swee[ks];
        const float s = (w > 0.f) ? 1.f : -1.f;
        const float wv1 = sW1[ks][h];
        c1 = fmaf(s * w, wv1, c1);
        c0 = fmaf(s * sbee[ks], wv1, c0);
        float* base = cT + (size_t)(iv * 37 + l4h * 9 + rh) * 4;
        base[2 * sub] = c1; base[2 * sub + 1] = c0;
      }
      thrS[h] = sth[h];
    }
    return;
  }

  // ---- binning path ----
  __shared__ int hist[NBKT], base[NBKT];
  if (t < NBKT) hist[t] = 0;
  __syncthreads();

  const int e0 = blockIdx.x * BIN_CHUNK;
  int srcv[8], dstv[8], loff[8];
  if (e0 + BIN_CHUNK <= NE) {  // full block: int4-vectorized loads (8 edges/thread)
    const int eb = e0 + t * 8;
    const int4 sa = *(const int4*)(ei + eb);
    const int4 sb = *(const int4*)(ei + eb + 4);
    const int4 da = *(const int4*)(ei + NE + eb);
    const int4 db = *(const int4*)(ei + NE + eb + 4);
    srcv[0] = sa.x; srcv[1] = sa.y; srcv[2] = sa.z; srcv[3] = sa.w;
    srcv[4] = sb.x; srcv[5] = sb.y; srcv[6] = sb.z; srcv[7] = sb.w;
    dstv[0] = da.x; dstv[1] = da.y; dstv[2] = da.z; dstv[3] = da.w;
    dstv[4] = db.x; dstv[5] = db.y; dstv[6] = db.z; dstv[7] = db.w;
#pragma unroll
    for (int j = 0; j < 8; ++j) loff[j] = atomicAdd(&hist[dstv[j] >> 8], 1);
  } else {  // tail block: guarded scalar path
#pragma unroll
    for (int j = 0; j < 8; ++j) {
      const int e = e0 + t * 8 + j;
      if (e < NE) {
        srcv[j] = ei[e];
        dstv[j] = ei[NE + e];
        loff[j] = atomicAdd(&hist[dstv[j] >> 8], 1);
      } else dstv[j] = -1;
    }
  }
  __syncthreads();
  if (t < NBKT) base[t] = atomicAdd(&gcur[t], hist[t]);
  __syncthreads();
#pragma unroll
  for (int j = 0; j < 8; ++j) {
    if (dstv[j] >= 0) {
      const int b = dstv[j] >> 8;
      const int pos = base[b] + loff[j];
      if (pos < BCAP)
        gbin[(size_t)b * BCAP + pos] =
            ((unsigned int)srcv[j] << 8) | (unsigned int)(dstv[j] & 255);
    }
  }
}

// ---------- pass 2: per-bucket exact CSR + rowrange + dinv (register-staged) ----------
__global__ __launch_bounds__(256) void k_pass2(const unsigned int* __restrict__ gbin,
                                               const int* __restrict__ gcur,
                                               unsigned short* __restrict__ gcsr,
                                               int2* __restrict__ rowrange,
                                               float* __restrict__ dinv) {
  __shared__ int hist[256], cur[256], sc[256];
  __shared__ unsigned short lcsr[BCAP];
  const int b = blockIdx.x, t = threadIdx.x;
  const int sz = min(gcur[b], BCAP);
  hist[t] = 0;
  __syncthreads();

  const unsigned int* bb = gbin + (size_t)b * BCAP;
  unsigned int ent[32];  // 32*256 = 8192 = BCAP, statically indexed
#pragma unroll
  for (int k = 0; k < 32; ++k) {
    const int i = t + k * 256;
    if (i < sz) {
      ent[k] = bb[i];
      atomicAdd(&hist[ent[k] & 255], 1);
    }
  }
  __syncthreads();

  int v = hist[t];
  const int cnt = v;
  sc[t] = v;
  __syncthreads();
#pragma unroll
  for (int off = 1; off < 256; off <<= 1) {
    const int o = (t >= off) ? sc[t - off] : 0;
    __syncthreads();
    v += o;
    sc[t] = v;
    __syncthreads();
  }
  const int ex = v - cnt;  // exclusive
  cur[t] = ex;
  const int d = b * 256 + t;
  if (d < NN) {
    const int beg = b * BCAP + ex;
    rowrange[d] = make_int2(beg, beg + cnt);
    dinv[d] = rsqrtf((float)(cnt + 1));
  }
  __syncthreads();

#pragma unroll
  for (int k = 0; k < 32; ++k) {
    const int i = t + k * 256;
    if (i < sz) {
      const unsigned int en = ent[k];
      const int off = atomicAdd(&cur[en & 255], 1);
      lcsr[off] = (unsigned short)(en >> 8);
    }
  }
  __syncthreads();
  {  // uint4 flush: 16B/thread; over-write within private BCAP region is dead data
    const int n4 = (sz + 7) >> 3;  // # of uint4 (8-entry) chunks
    uint4* gdst = (uint4*)(gcsr + (size_t)b * BCAP);
    const uint4* lsrc = (const uint4*)lcsr;
    for (int i = t; i < n4; i += 256) gdst[i] = lsrc[i];
  }
}

// ---------- node encoder + h0@W_gcn; htb = bf16(ht * dinv[n]) ----------
__global__ __launch_bounds__(256) void k_node(
    const float* __restrict__ x, const float* __restrict__ W_ne,
    const float* __restrict__ b_ne, const float* __restrict__ W_gcn,
    const float* __restrict__ dinv, unsigned short* __restrict__ htb) {
  __shared__ float sh[4][H];
  const int lane = threadIdx.x & 63;
  const int wv   = threadIdx.x >> 6;
  const int n    = blockIdx.x * 4 + wv;

  float acc = b_ne[lane];
#pragma unroll
  for (int k = 0; k < 5; ++k) acc = fmaf(x[n * 5 + k], W_ne[k * H + lane], acc);
  acc = fmaxf(acc, 0.0f);
  sh[wv][lane] = acc;
  __syncthreads();

  float hv = 0.0f;
#pragma unroll 8
  for (int k = 0; k < H; ++k) hv = fmaf(sh[wv][k], W_gcn[k * H + lane], hv);

  htb[(size_t)n * H + lane] = f2bf(hv * dinv[n]);
}

// ---------- fused gather + uv: block = 16 nodes; LDS handoff (XOR-swizzled) ----------
__global__ __launch_bounds__(256) void k_gather_uv(
    const int2* __restrict__ rowrange, const unsigned short* __restrict__ gcsr,
    const unsigned short* __restrict__ htb, const float* __restrict__ dinv,
    const float* __restrict__ b_gcn, const unsigned short* __restrict__ w1f,
    unsigned short* __restrict__ u, unsigned short* __restrict__ v) {
  __shared__ unsigned short shg[16 * 64];  // 2KB, bf16 hg tile, XOR-swizzled rows
  const int lane = threadIdx.x & 63;
  const int wv   = threadIdx.x >> 6;
  const int n0   = blockIdx.x * 16;  // NN/16 = 3125 blocks exact
  const float bg = b_gcn[lane];

#pragma unroll 1
  for (int q = 0; q < 4; ++q) {
    const int nl = wv * 4 + q;
    const int n  = n0 + nl;
    const int2 rr = rowrange[n];
    float sum = bf2f(htb[(size_t)n * H + lane]);  // self-loop
    int i = rr.x;
#pragma unroll 1
    for (; i + 8 <= rr.y; i += 8) {
      const int s0 = gcsr[i],     s1 = gcsr[i + 1];
      const int s2 = gcsr[i + 2], s3 = gcsr[i + 3];
      const int s4 = gcsr[i + 4], s5 = gcsr[i + 5];
      const int s6 = gcsr[i + 6], s7 = gcsr[i + 7];
      const float v0 = bf2f(htb[(size_t)s0 * H + lane]);
      const float v1 = bf2f(htb[(size_t)s1 * H + lane]);
      const float v2 = bf2f(htb[(size_t)s2 * H + lane]);
      const float v3 = bf2f(htb[(size_t)s3 * H + lane]);
      const float v4 = bf2f(htb[(size_t)s4 * H + lane]);
      const float v5 = bf2f(htb[(size_t)s5 * H + lane]);
      const float v6 = bf2f(htb[(size_t)s6 * H + lane]);
      const float v7 = bf2f(htb[(size_t)s7 * H + lane]);
      sum += ((v0 + v1) + (v2 + v3)) + ((v4 + v5) + (v6 + v7));
    }
#pragma unroll 1
    for (; i < rr.y; ++i) sum += bf2f(htb[(size_t)gcsr[i] * H + lane]);

    const float hgv = fmaf(dinv[n], sum, bg);
    shg[((nl * 128 + lane * 2) ^ ((nl & 7) << 4)) >> 1] = f2bf(hgv);
  }
  __syncthreads();

  const int l15 = lane & 15, l4 = lane >> 4;
  const bf16x8 a0 = *(const bf16x8*)(shg + (((l15 * 128 + l4 * 16) ^ ((l15 & 7) << 4)) >> 1));
  const bf16x8 a1 = *(const bf16x8*)(shg + (((l15 * 128 + 64 + l4 * 16) ^ ((l15 & 7) << 4)) >> 1));

  const int ct = wv;  // this wave's output column tile
  const bf16x8 bu0 = *(const bf16x8*)(w1f + ((ct * 2 + 0) * 64 + lane) * 8);
  const bf16x8 bu1 = *(const bf16x8*)(w1f + ((ct * 2 + 1) * 64 + lane) * 8);
  const bf16x8 bv0 = *(const bf16x8*)(w1f + ((8 + ct * 2 + 0) * 64 + lane) * 8);
  const bf16x8 bv1 = *(const bf16x8*)(w1f + ((8 + ct * 2 + 1) * 64 + lane) * 8);

  f32x4 au = (f32x4)(0.f), av = (f32x4)(0.f);
  au = __builtin_amdgcn_mfma_f32_16x16x32_bf16(a0, bu0, au, 0, 0, 0);
  au = __builtin_amdgcn_mfma_f32_16x16x32_bf16(a1, bu1, au, 0, 0, 0);
  av = __builtin_amdgcn_mfma_f32_16x16x32_bf16(a0, bv0, av, 0, 0, 0);
  av = __builtin_amdgcn_mfma_f32_16x16x32_bf16(a1, bv1, av, 0, 0, 0);

#pragma unroll
  for (int r = 0; r < 4; ++r) {  // D: row = l4*4+r (node), col = l15
    const size_t idx = (size_t)(n0 + l4 * 4 + r) * H + ct * 16 + l15;
    u[idx] = f2bf(au[r]);
    v[idx] = f2bf(av[r]);
  }
}

// ---------- edge kernel helpers ----------
__device__ __forceinline__ int find_iv(const float* __restrict__ sThr, float ea) {
  int iv = 0;
#pragma unroll
  for (int st = 64; st >= 1; st >>= 1) {
    const int nc = iv + st;
    if (nc <= 64 && sThr[nc - 1] <= ea) iv = nc;
  }
  return iv;
}

__device__ __forceinline__ void edge_compute(
    float ea, uint4 U0, uint4 U1, uint4 V0, uint4 V1,
    const float* __restrict__ sThr, const float4* __restrict__ sCT4,
    const float* __restrict__ w2v, int l4, int lane, float b2v,
    float* __restrict__ out, int obase) {
  const int iv = find_iv(sThr, ea);
  const float4* cp = sCT4 + iv * 37 + l4 * 9;  // bank-spread layout
  const unsigned int ud[8] = {U0.x, U0.y, U0.z, U0.w, U1.x, U1.y, U1.z, U1.w};
  const unsigned int vd[8] = {V0.x, V0.y, V0.z, V0.w, V1.x, V1.y, V1.z, V1.w};
  float p = 0.f;
#pragma unroll
  for (int r = 0; r < 8; ++r) {
    const float4 cc = cp[r];  // (c1,c0) for h = l4*16 + 2r, 2r+1
    const float ulo = __builtin_bit_cast(float, ud[r] << 16);
    const float uhi = __builtin_bit_cast(float, ud[r] & 0xFFFF0000u);
    const float vlo = __builtin_bit_cast(float, vd[r] << 16);
    const float vhi = __builtin_bit_cast(float, vd[r] & 0xFFFF0000u);
    const float z0 = ulo + vlo + fmaf(ea, cc.x, cc.y);
    const float z1 = uhi + vhi + fmaf(ea, cc.z, cc.w);
    p = fmaf(fmaxf(z0, 0.f), w2v[2 * r], p);
    p = fmaf(fmaxf(z1, 0.f), w2v[2 * r + 1], p);
  }
  p += __shfl_xor(p, 16);
  p += __shfl_xor(p, 32);
  if (lane < 16) out[obase + lane] = p + b2v;
}

// ---------- edge kernel: 512 threads (8 waves), LDS sCT4 reused over 2 chunks ----------
__global__ __launch_bounds__(512) void k_edge(
    const int* __restrict__ ei, const float* __restrict__ eattr,
    const unsigned short* __restrict__ u, const unsigned short* __restrict__ v,
    const float* __restrict__ thrS, const float* __restrict__ cT,
    const float* __restrict__ W2, const float* __restrict__ b2,
    float* __restrict__ out) {
  __shared__ float sThr[64];
  __shared__ float4 sCT4[CT4N];  // 38,480 B

  const int t = threadIdx.x;
  if (t < 64) sThr[t] = thrS[t];
  {
    const float4* g = (const float4*)cT;
    for (int i = t; i < CT4N; i += 512) sCT4[i] = g[i];
  }
  __syncthreads();

  const int lane = t & 63;
  const int wv   = t >> 6;  // 0..7
  const int l15  = lane & 15, l4 = lane >> 4;
  const float b2v = b2[0];

  float w2v[16];
#pragma unroll
  for (int j = 0; j < 16; ++j) w2v[j] = W2[l4 * 16 + j];

#pragma unroll 1
  for (int c = 0; c < ECHUNK; ++c) {
    const int tile0 = (((c * 625) + blockIdx.x) * 8 + wv) * ET;
    int srcA[ET], dstA[ET];
    float eaA[ET];
#pragma unroll
    for (int tt = 0; tt < ET; ++tt) {
      srcA[tt] = ei[(tile0 + tt) * 16 + l15];
      dstA[tt] = ei[NE + (tile0 + tt) * 16 + l15];
      eaA[tt]  = eattr[(tile0 + tt) * 16 + l15];
    }

    uint4 Au0, Au1, Av0, Av1, Bu0, Bu1, Bv0, Bv1;

#define LOADUV(U0, U1, V0, V1, tt) {                               \
    const unsigned short* up = u + (size_t)srcA[tt] * H + l4 * 16; \
    const unsigned short* vp = v + (size_t)dstA[tt] * H + l4 * 16; \
    U0 = *(const uint4*)(up); U1 = *(const uint4*)(up + 8);        \
    V0 = *(const uint4*)(vp); V1 = *(const uint4*)(vp + 8); }

    LOADUV(Au0, Au1, Av0, Av1, 0);
    LOADUV(Bu0, Bu1, Bv0, Bv1, 1);
    edge_compute(eaA[0], Au0, Au1, Av0, Av1, sThr, sCT4, w2v, l4, lane, b2v, out, (tile0 + 0) * 16);
    LOADUV(Au0, Au1, Av0, Av1, 2);
    edge_compute(eaA[1], Bu0, Bu1, Bv0, Bv1, sThr, sCT4, w2v, l4, lane, b2v, out, (tile0 + 1) * 16);
    LOADUV(Bu0, Bu1, Bv0, Bv1, 3);
    edge_compute(eaA[2], Au0, Au1, Av0, Av1, sThr, sCT4, w2v, l4, lane, b2v, out, (tile0 + 2) * 16);
    LOADUV(Au0, Au1, Av0, Av1, 4);
    edge_compute(eaA[3], Bu0, Bu1, Bv0, Bv1, sThr, sCT4, w2v, l4, lane, b2v, out, (tile0 + 3) * 16);
    edge_compute(eaA[4], Au0, Au1, Av0, Av1, sThr, sCT4, w2v, l4, lane, b2v, out, (tile0 + 4) * 16);
#undef LOADUV
  }
}

extern "C" void kernel_launch(void* const* d_in, const int* in_sizes, int n_in,
                              void* d_out, int out_size, void* d_ws, size_t ws_size,
                              hipStream_t stream) {
  const float* x     = (const float*)d_in[0];
  const int*   ei    = (const int*)d_in[1];
  const float* eattr = (const float*)d_in[2];
  const float* W_ne  = (const float*)d_in[3];
  const float* b_ne  = (const float*)d_in[4];
  const float* W_ee  = (const float*)d_in[5];
  const float* b_ee  = (const float*)d_in[6];
  const float* W_gcn = (const float*)d_in[7];
  const float* b_gcn = (const float*)d_in[8];
  const float* W1    = (const float*)d_in[9];
  const float* b1    = (const float*)d_in[10];
  const float* W2    = (const float*)d_in[11];
  const float* b2    = (const float*)d_in[12];
  float* out = (float*)d_out;

  char* ws = (char*)d_ws;
  unsigned short* htb = (unsigned short*)(ws + 0);         // 6.4MB
  unsigned short* uT  = (unsigned short*)(ws + 6400000);   // 6.4MB
  unsigned int*   gbin = (unsigned int*)(ws + 12800000);   // 6,422,528
  unsigned short* vT  = (unsigned short*)(ws + 12800000);  // overlays gbin (dead after pass2)
  unsigned short* gcsr = (unsigned short*)(ws + 19222528); // 3,211,264
  int2*  rowrange = (int2*)(ws + 22433792);                // 400,000
  float* dinv    = (float*)(ws + 22833792);                // 200,000
  int*   gcur    = (int*)(ws + 23033792);                  // 784
  float* thrS    = (float*)(ws + 23034592);                // 256
  float* cT      = (float*)(ws + 23034848);                // float4[65*37] = 38,480
  unsigned short* w1f = (unsigned short*)(ws + 23073328);  // 16,384

  hipMemsetAsync(gcur, 0, NBKT * sizeof(int), stream);
  k_bin<<<NBIN + 2, 256, 0, stream>>>(ei, gbin, gcur, W1, b1, W_ee, b_ee, thrS, cT, w1f);
  k_pass2<<<NBKT, 256, 0, stream>>>(gbin, gcur, gcsr, rowrange, dinv);
  k_node<<<NN / 4, 256, 0, stream>>>(x, W_ne, b_ne, W_gcn, dinv, htb);
  k_gather_uv<<<NN / 16, 256, 0, stream>>>(rowrange, gcsr, htb, dinv, b_gcn, w1f, uT, vT);
  k_edge<<<625, 512, 0, stream>>>(ei, eattr, uT, vT, thrS, cT, W2, b2, out);
}